// Round 2
// baseline (18780.771 us; speedup 1.0000x reference)
//
#include <hip/hip_runtime.h>
#include <stdint.h>

typedef unsigned short u16;
typedef unsigned int   u32;
typedef short bf16x8 __attribute__((ext_vector_type(8)));
typedef float f32x4  __attribute__((ext_vector_type(4)));

static_assert(sizeof(bf16x8) == 16, "bf16x8 must be 16B");

#define LOG2E 1.4426950408889634f
#define TCH 32   // timesteps per chunk

__device__ __forceinline__ float bf2f(u16 u) { return __builtin_bit_cast(float, ((u32)u) << 16); }
__device__ __forceinline__ u16 f2bf(float f) {
  u32 x = __builtin_bit_cast(u32, f);
  return (u16)((x + 0x7fffu + ((x >> 16) & 1u)) >> 16);   // RNE, inputs are tame (no NaN)
}
__device__ __forceinline__ float sigm(float x) {
  return __builtin_amdgcn_rcpf(1.f + __builtin_amdgcn_exp2f(-LOG2E * x));
}
__device__ __forceinline__ float tanh_(float x) {
  return 1.f - 2.f * __builtin_amdgcn_rcpf(1.f + __builtin_amdgcn_exp2f(2.f * LOG2E * x));
}
__device__ __forceinline__ bf16x8 cvt8(const float* p) {
  bf16x8 r;
  #pragma unroll
  for (int j = 0; j < 8; ++j) r[j] = (short)f2bf(p[j]);
  return r;
}

// ---------------- prep kernels ----------------
__global__ void k_cvt(const float* __restrict__ src, u16* __restrict__ dst, int n) {
  int i = blockIdx.x * blockDim.x + threadIdx.x;
  int st = gridDim.x * blockDim.x;
  for (; i < n; i += st) dst[i] = f2bf(src[i]);
}

__global__ void k_bias(const float* __restrict__ bi0, const float* __restrict__ bh0,
                       const float* __restrict__ bi, const float* __restrict__ bh,
                       float* __restrict__ out) {
  int i = blockIdx.x * blockDim.x + threadIdx.x;
  if (i < 4096) out[i] = bi0[i] + bh0[i];
  else if (i < 20480) out[i] = bi[i - 4096] + bh[i - 4096];
}

// ---------------- input GEMM over one time-chunk ----------------
// gx[d][hb][tt][q][b][u] = X_t @ Wi^T + bias   (bf16, scan-blocked layout)
// Layer 0: A rows gathered from embed[tokens[.]] fp32 on the fly.
__global__ __launch_bounds__(256) void k_gemm(
    const u16* __restrict__ X, const float* __restrict__ emb, const int* __restrict__ tok,
    const u16* __restrict__ Wi, const float* __restrict__ bias,
    u16* __restrict__ gx, int K, int t0)
{
  int d   = blockIdx.x >> 4;     // direction
  int nt0 = blockIdx.x & 15;     // N tile (128 gates)
  int tt  = blockIdx.y;          // timestep within chunk
  int t   = t0 + tt;
  __shared__ u16 As[128 * 64];
  __shared__ u16 Bs[128 * 64];
  __shared__ int s_tok[128];
  int tid = threadIdx.x, lane = tid & 63, w = tid >> 6;
  int wm = w & 1, wn = w >> 1;
  if (tok && tid < 128) s_tok[tid] = tok[t * 128 + tid];
  __syncthreads();

  const u16* Bbase = Wi + ((size_t)d * 2048 + nt0 * 128) * K;
  f32x4 acc[4][4];
  #pragma unroll
  for (int a = 0; a < 4; ++a)
    #pragma unroll
    for (int b = 0; b < 4; ++b) acc[a][b] = f32x4{0.f, 0.f, 0.f, 0.f};

  int nkt = K >> 6;  // K-tiles of 64
  for (int kt = 0; kt < nkt; ++kt) {
    #pragma unroll
    for (int i = 0; i < 4; ++i) {
      int s = tid + i * 256;              // slot 0..1023
      int row = s >> 3, c = s & 7;
      int cs = c ^ (row & 7);             // XOR-swizzle kills ds_read bank conflicts
      bf16x8 va;
      if (tok) {
        va = cvt8(emb + (size_t)s_tok[row] * 320 + kt * 64 + c * 8);
      } else {
        va = *(const bf16x8*)(X + ((size_t)t * 128 + row) * K + kt * 64 + c * 8);
      }
      bf16x8 vb = *(const bf16x8*)(Bbase + (size_t)row * K + kt * 64 + c * 8);
      *(bf16x8*)(&As[(row * 8 + cs) * 8]) = va;
      *(bf16x8*)(&Bs[(row * 8 + cs) * 8]) = vb;
    }
    __syncthreads();
    #pragma unroll
    for (int kk2 = 0; kk2 < 2; ++kk2) {
      int cl = kk2 * 4 + (lane >> 4);
      bf16x8 af[4], bfr[4];
      #pragma unroll
      for (int mt = 0; mt < 4; ++mt) {
        int row = wm * 64 + mt * 16 + (lane & 15);
        af[mt] = *(const bf16x8*)(&As[(row * 8 + (cl ^ (row & 7))) * 8]);
      }
      #pragma unroll
      for (int nt = 0; nt < 4; ++nt) {
        int row = wn * 64 + nt * 16 + (lane & 15);
        bfr[nt] = *(const bf16x8*)(&Bs[(row * 8 + (cl ^ (row & 7))) * 8]);
      }
      #pragma unroll
      for (int mt = 0; mt < 4; ++mt)
        #pragma unroll
        for (int nt = 0; nt < 4; ++nt)
          acc[mt][nt] = __builtin_amdgcn_mfma_f32_16x16x32_bf16(af[mt], bfr[nt], acc[mt][nt], 0, 0, 0);
    }
    __syncthreads();
  }
  // epilogue: + bias, write bf16 into scan-blocked layout
  #pragma unroll
  for (int nt = 0; nt < 4; ++nt) {
    int g = nt0 * 128 + wn * 64 + nt * 16 + (lane & 15);
    float bv = bias[d * 2048 + g];
    int q = g >> 9, hbb = (g >> 4) & 31, u = g & 15;
    size_t base = ((((size_t)d * 32 + hbb) * TCH + tt) * 4 + q) * 2048 + u;
    #pragma unroll
    for (int mt = 0; mt < 4; ++mt)
      #pragma unroll
      for (int r = 0; r < 4; ++r) {
        int b = wm * 64 + mt * 16 + (lane >> 4) * 4 + r;
        gx[base + (size_t)b * 16] = f2bf(acc[mt][nt][r] + bv);
      }
  }
}

// ---------------- grid barrier: single cnt/gen pair, agent scope ----------------
__device__ __forceinline__ void gridbar(u32* cnt, u32* gen) {
  __syncthreads();                       // all waves done with this step's stores
  if (threadIdx.x == 0) {
    __threadfence();                     // release: wbl2 — push h to coherent point
    u32 g = __hip_atomic_load(gen, __ATOMIC_RELAXED, __HIP_MEMORY_SCOPE_AGENT);
    u32 old = __hip_atomic_fetch_add(cnt, 1u, __ATOMIC_ACQ_REL, __HIP_MEMORY_SCOPE_AGENT);
    if (old == 63u) {                    // last to arrive
      __hip_atomic_store(cnt, 0u, __ATOMIC_RELAXED, __HIP_MEMORY_SCOPE_AGENT);
      __hip_atomic_store(gen, g + 1u, __ATOMIC_RELEASE, __HIP_MEMORY_SCOPE_AGENT);
    } else {
      while (__hip_atomic_load(gen, __ATOMIC_RELAXED, __HIP_MEMORY_SCOPE_AGENT) == g)
        __builtin_amdgcn_s_sleep(1);
    }
    __threadfence();                     // acquire: buffer_inv — drop stale L1/L2
  }
  __syncthreads();
}

// 64 persistent blocks (<=1/CU). Block = (d, hb): owns h cols [hb*16, hb*16+16).
// Wh slice (64 gate rows x 512) converted fp32->bf16 into LDS, swizzled.
__global__ __launch_bounds__(256) void k_scan(
    const float* __restrict__ Whf, const u16* __restrict__ gx,
    u16* __restrict__ hbuf,     // [pp=2][d=2][128][512] bf16, parity = global t
    u16* __restrict__ xout,     // [32768][1024] bf16 (concat dirs)
    float* __restrict__ cbuf,   // [2][128][512] f32
    u32* cnt, u32* gen, int t0)
{
  int tid = threadIdx.x, lane = tid & 63, w = tid >> 6;
  int d = blockIdx.x >> 5, hb = blockIdx.x & 31;
  __shared__ u16 WhL[64 * 512];
  for (int i = tid; i < 64 * 512; i += 256) {
    int r = i >> 9, k = i & 511;
    int grow = (r >> 4) * 512 + hb * 16 + (r & 15);       // gate row q*512 + hb*16 + u
    WhL[(r << 9) + (k ^ ((r & 7) << 3))] = f2bf(Whf[((size_t)d * 2048 + grow) * 512 + k]);
  }

  int bb = w * 32;                 // wave owns batch rows [bb, bb+32)
  int l15 = lane & 15, l4 = lane >> 4;
  float c[2][4];
  if (t0 == 0) {
    #pragma unroll
    for (int mt = 0; mt < 2; ++mt)
      #pragma unroll
      for (int r = 0; r < 4; ++r) c[mt][r] = 0.f;
    for (int i = tid; i < 2048; i += 256) {               // zero own h_{-1} cols, pp=0
      int b = i >> 4, u = i & 15;
      hbuf[((size_t)d * 128 + b) * 512 + hb * 16 + u] = 0;
    }
    gridbar(cnt, gen);
  } else {
    #pragma unroll
    for (int mt = 0; mt < 2; ++mt)
      #pragma unroll
      for (int r = 0; r < 4; ++r) {
        int b = bb + mt * 16 + l4 * 4 + r;
        c[mt][r] = cbuf[((size_t)d * 128 + b) * 512 + hb * 16 + l15];
      }
    __syncthreads();   // WhL staging complete (no gridbar needed: h already global)
  }

  for (int tt = 0; tt < TCH; ++tt) {
    int t = t0 + tt;
    const u16* gxt = gx + (((size_t)d * 32 + hb) * TCH + tt) * 8192;
    u16 gxv[2][4][4];
    #pragma unroll
    for (int mt = 0; mt < 2; ++mt)
      #pragma unroll
      for (int q = 0; q < 4; ++q)
        #pragma unroll
        for (int r = 0; r < 4; ++r) {
          int b = bb + mt * 16 + l4 * 4 + r;
          gxv[mt][q][r] = gxt[(q * 128 + b) * 16 + l15];
        }
    f32x4 acc[2][4];
    #pragma unroll
    for (int mt = 0; mt < 2; ++mt)
      #pragma unroll
      for (int q = 0; q < 4; ++q) acc[mt][q] = f32x4{0.f, 0.f, 0.f, 0.f};
    const u16* hp = hbuf + ((size_t)(t & 1) * 2 + d) * 128 * 512;
    #pragma unroll
    for (int kk = 0; kk < 16; ++kk) {
      int kbase = kk * 32 + l4 * 8;
      bf16x8 a0 = *(const bf16x8*)(hp + (size_t)(bb + l15) * 512 + kbase);
      bf16x8 a1 = *(const bf16x8*)(hp + (size_t)(bb + 16 + l15) * 512 + kbase);
      #pragma unroll
      for (int q = 0; q < 4; ++q) {
        int r = q * 16 + l15;
        bf16x8 bv = *(const bf16x8*)(&WhL[(r << 9) + (kbase ^ ((r & 7) << 3))]);
        acc[0][q] = __builtin_amdgcn_mfma_f32_16x16x32_bf16(a0, bv, acc[0][q], 0, 0, 0);
        acc[1][q] = __builtin_amdgcn_mfma_f32_16x16x32_bf16(a1, bv, acc[1][q], 0, 0, 0);
      }
    }
    u16* ho = hbuf + ((size_t)((t + 1) & 1) * 2 + d) * 128 * 512;
    #pragma unroll
    for (int mt = 0; mt < 2; ++mt)
      #pragma unroll
      for (int r = 0; r < 4; ++r) {
        int b = bb + mt * 16 + l4 * 4 + r;
        float gi = acc[mt][0][r] + bf2f(gxv[mt][0][r]);
        float gf = acc[mt][1][r] + bf2f(gxv[mt][1][r]);
        float gg = acc[mt][2][r] + bf2f(gxv[mt][2][r]);
        float go = acc[mt][3][r] + bf2f(gxv[mt][3][r]);
        float cn = sigm(gf) * c[mt][r] + sigm(gi) * tanh_(gg);
        float hn = sigm(go) * tanh_(cn);
        c[mt][r] = cn;
        u16 hv = f2bf(hn);
        ho[(size_t)b * 512 + hb * 16 + l15] = hv;
        xout[((size_t)t * 128 + b) * 1024 + d * 512 + hb * 16 + l15] = hv;
      }
    if (tt < TCH - 1) gridbar(cnt, gen);   // last step: kernel boundary syncs
  }
  // save c state for next chunk
  #pragma unroll
  for (int mt = 0; mt < 2; ++mt)
    #pragma unroll
    for (int r = 0; r < 4; ++r) {
      int b = bb + mt * 16 + l4 * 4 + r;
      cbuf[((size_t)d * 128 + b) * 512 + hb * 16 + l15] = c[mt][r];
    }
}

// ---------------- final: max over directions ----------------
__global__ void k_final(const u16* __restrict__ xin, float* __restrict__ out, int n) {
  int i = blockIdx.x * 256 + threadIdx.x;
  if (i >= n) return;
  int nrow = i >> 9, j = i & 511;
  float a = bf2f(xin[(size_t)nrow * 1024 + j]);
  float b = bf2f(xin[(size_t)nrow * 1024 + 512 + j]);
  out[i] = fmaxf(a, b);
}

extern "C" void kernel_launch(void* const* d_in, const int* in_sizes, int n_in,
                              void* d_out, int out_size, void* d_ws, size_t ws_size,
                              hipStream_t stream) {
  (void)in_sizes; (void)n_in; (void)out_size; (void)ws_size;
  const int*   tokens = (const int*)d_in[0];
  const float* embedW = (const float*)d_in[1];
  const float* W_ih0  = (const float*)d_in[2];
  const float* W_hh0  = (const float*)d_in[3];
  const float* b_ih0  = (const float*)d_in[4];
  const float* b_hh0  = (const float*)d_in[5];
  const float* W_ih   = (const float*)d_in[6];
  const float* W_hh   = (const float*)d_in[7];
  const float* b_ih   = (const float*)d_in[8];
  const float* b_hh   = (const float*)d_in[9];

  char* ws = (char*)d_ws;
  size_t off = 0;
  auto alloc = [&](size_t bytes) { void* p = ws + off; off += (bytes + 255) & ~(size_t)255; return p; };
  u16*   Wi_bf = (u16*)alloc(18087936ull * 2);   // [2][2048][320] + [4][2][2048][1024]
  float* biasC = (float*)alloc(20480ull * 4);    // [5][2][2048]
  u16*   Xbuf  = (u16*)alloc(33554432ull * 2);   // [32768][1024] single activation buffer
  u16*   gxbuf = (u16*)alloc(16777216ull * 2);   // [2][32][TCH][4][128][16] one chunk
  u16*   hbuf  = (u16*)alloc(262144ull * 2);     // [2][2][128][512]
  float* cbuf  = (float*)alloc(131072ull * 4);   // [2][128][512]
  u32*   flags = (u32*)alloc(256);               // cnt @0, gen @32
  // total ~132 MB

  hipMemsetAsync(flags, 0, 256, stream);

  k_cvt<<<1024, 256, 0, stream>>>(W_ih0, Wi_bf, 1310720);
  k_cvt<<<4096, 256, 0, stream>>>(W_ih,  Wi_bf + 1310720, 16777216);
  k_bias<<<80, 256, 0, stream>>>(b_ih0, b_hh0, b_ih, b_hh, biasC);

  for (int l = 0; l < 5; ++l) {
    int K = l ? 1024 : 320;
    const u16*   Wi_l  = l ? (Wi_bf + 1310720 + (size_t)(l - 1) * 4194304) : Wi_bf;
    const float* Whf_l = l ? (W_hh + (size_t)(l - 1) * 2097152) : W_hh0;
    const float* bias_l = biasC + (size_t)l * 4096;
    const float* embA = (l == 0) ? embedW : nullptr;
    const int*   tokA = (l == 0) ? tokens : nullptr;
    for (int ch = 0; ch < 256 / TCH; ++ch) {
      dim3 gg(32, TCH, 1);
      k_gemm<<<gg, 256, 0, stream>>>(Xbuf, embA, tokA, Wi_l, bias_l, gxbuf, K, ch * TCH);
      k_scan<<<64, 256, 0, stream>>>(Whf_l, gxbuf, hbuf, Xbuf, cbuf, flags, flags + 32, ch * TCH);
    }
  }
  k_final<<<65536, 256, 0, stream>>>(Xbuf, (float*)d_out, 16777216);
}

// Round 3
// 16916.696 us; speedup vs baseline: 1.1102x; 1.1102x over previous
//
#include <hip/hip_runtime.h>
#include <stdint.h>

typedef unsigned short u16;
typedef unsigned int   u32;
typedef unsigned long long u64;
typedef short bf16x8 __attribute__((ext_vector_type(8)));
typedef float f32x4  __attribute__((ext_vector_type(4)));

static_assert(sizeof(bf16x8) == 16, "bf16x8 must be 16B");

#define LOG2E 1.4426950408889634f
#define TCH 32   // timesteps per chunk

__device__ __forceinline__ float bf2f(u16 u) { return __builtin_bit_cast(float, ((u32)u) << 16); }
__device__ __forceinline__ u16 f2bf(float f) {
  u32 x = __builtin_bit_cast(u32, f);
  return (u16)((x + 0x7fffu + ((x >> 16) & 1u)) >> 16);   // RNE, inputs are tame (no NaN)
}
__device__ __forceinline__ float sigm(float x) {
  return __builtin_amdgcn_rcpf(1.f + __builtin_amdgcn_exp2f(-LOG2E * x));
}
__device__ __forceinline__ float tanh_(float x) {
  return 1.f - 2.f * __builtin_amdgcn_rcpf(1.f + __builtin_amdgcn_exp2f(2.f * LOG2E * x));
}
__device__ __forceinline__ bf16x8 cvt8(const float* p) {
  bf16x8 r;
  #pragma unroll
  for (int j = 0; j < 8; ++j) r[j] = (short)f2bf(p[j]);
  return r;
}

// ---- coherent (agent-scope, MALL-level) access helpers: no fences needed ----
union U16x8 { u64 q[2]; bf16x8 v; };
__device__ __forceinline__ bf16x8 ldh16(const u16* p) {   // 16B coherent load (2x u64)
  U16x8 u;
  u.q[0] = __hip_atomic_load((const u64*)p,     __ATOMIC_RELAXED, __HIP_MEMORY_SCOPE_AGENT);
  u.q[1] = __hip_atomic_load((const u64*)p + 1, __ATOMIC_RELAXED, __HIP_MEMORY_SCOPE_AGENT);
  return u.v;
}
__device__ __forceinline__ void sth(u16* p, u16 v) {      // 2B coherent store
  __hip_atomic_store(p, v, __ATOMIC_RELAXED, __HIP_MEMORY_SCOPE_AGENT);
}

// ---------------- prep kernels ----------------
__global__ void k_cvt(const float* __restrict__ src, u16* __restrict__ dst, int n) {
  int i = blockIdx.x * blockDim.x + threadIdx.x;
  int st = gridDim.x * blockDim.x;
  for (; i < n; i += st) dst[i] = f2bf(src[i]);
}

__global__ void k_bias(const float* __restrict__ bi0, const float* __restrict__ bh0,
                       const float* __restrict__ bi, const float* __restrict__ bh,
                       float* __restrict__ out) {
  int i = blockIdx.x * blockDim.x + threadIdx.x;
  if (i < 4096) out[i] = bi0[i] + bh0[i];
  else if (i < 20480) out[i] = bi[i - 4096] + bh[i - 4096];
}

// ---------------- input GEMM over one time-chunk ----------------
__global__ __launch_bounds__(256) void k_gemm(
    const u16* __restrict__ X, const float* __restrict__ emb, const int* __restrict__ tok,
    const u16* __restrict__ Wi, const float* __restrict__ bias,
    u16* __restrict__ gx, int K, int t0)
{
  int d   = blockIdx.x >> 4;     // direction
  int nt0 = blockIdx.x & 15;     // N tile (128 gates)
  int tt  = blockIdx.y;          // timestep within chunk
  int t   = t0 + tt;
  __shared__ u16 As[128 * 64];
  __shared__ u16 Bs[128 * 64];
  __shared__ int s_tok[128];
  int tid = threadIdx.x, lane = tid & 63, w = tid >> 6;
  int wm = w & 1, wn = w >> 1;
  if (tok && tid < 128) s_tok[tid] = tok[t * 128 + tid];
  __syncthreads();

  const u16* Bbase = Wi + ((size_t)d * 2048 + nt0 * 128) * K;
  f32x4 acc[4][4];
  #pragma unroll
  for (int a = 0; a < 4; ++a)
    #pragma unroll
    for (int b = 0; b < 4; ++b) acc[a][b] = f32x4{0.f, 0.f, 0.f, 0.f};

  int nkt = K >> 6;  // K-tiles of 64
  for (int kt = 0; kt < nkt; ++kt) {
    #pragma unroll
    for (int i = 0; i < 4; ++i) {
      int s = tid + i * 256;              // slot 0..1023
      int row = s >> 3, c = s & 7;
      int cs = c ^ (row & 7);             // XOR-swizzle kills ds_read bank conflicts
      bf16x8 va;
      if (tok) {
        va = cvt8(emb + (size_t)s_tok[row] * 320 + kt * 64 + c * 8);
      } else {
        va = *(const bf16x8*)(X + ((size_t)t * 128 + row) * K + kt * 64 + c * 8);
      }
      bf16x8 vb = *(const bf16x8*)(Bbase + (size_t)row * K + kt * 64 + c * 8);
      *(bf16x8*)(&As[(row * 8 + cs) * 8]) = va;
      *(bf16x8*)(&Bs[(row * 8 + cs) * 8]) = vb;
    }
    __syncthreads();
    #pragma unroll
    for (int kk2 = 0; kk2 < 2; ++kk2) {
      int cl = kk2 * 4 + (lane >> 4);
      bf16x8 af[4], bfr[4];
      #pragma unroll
      for (int mt = 0; mt < 4; ++mt) {
        int row = wm * 64 + mt * 16 + (lane & 15);
        af[mt] = *(const bf16x8*)(&As[(row * 8 + (cl ^ (row & 7))) * 8]);
      }
      #pragma unroll
      for (int nt = 0; nt < 4; ++nt) {
        int row = wn * 64 + nt * 16 + (lane & 15);
        bfr[nt] = *(const bf16x8*)(&Bs[(row * 8 + (cl ^ (row & 7))) * 8]);
      }
      #pragma unroll
      for (int mt = 0; mt < 4; ++mt)
        #pragma unroll
        for (int nt = 0; nt < 4; ++nt)
          acc[mt][nt] = __builtin_amdgcn_mfma_f32_16x16x32_bf16(af[mt], bfr[nt], acc[mt][nt], 0, 0, 0);
    }
    __syncthreads();
  }
  #pragma unroll
  for (int nt = 0; nt < 4; ++nt) {
    int g = nt0 * 128 + wn * 64 + nt * 16 + (lane & 15);
    float bv = bias[d * 2048 + g];
    int q = g >> 9, hbb = (g >> 4) & 31, u = g & 15;
    size_t base = ((((size_t)d * 32 + hbb) * TCH + tt) * 4 + q) * 2048 + u;
    #pragma unroll
    for (int mt = 0; mt < 4; ++mt)
      #pragma unroll
      for (int r = 0; r < 4; ++r) {
        int b = wm * 64 + mt * 16 + (lane >> 4) * 4 + r;
        gx[base + (size_t)b * 16] = f2bf(acc[mt][nt][r] + bv);
      }
  }
}

// ---------------- grid barrier: monotonic counter at MALL, fence-free ----------------
__device__ __forceinline__ void gridbar(u32* cnt, u32 target) {
  __syncthreads();   // drains vmcnt: all this block's coherent h-stores are at MALL
  if (threadIdx.x == 0) {
    __hip_atomic_fetch_add(cnt, 1u, __ATOMIC_RELAXED, __HIP_MEMORY_SCOPE_AGENT);
    while (__hip_atomic_load(cnt, __ATOMIC_RELAXED, __HIP_MEMORY_SCOPE_AGENT) < target) {}
  }
  __syncthreads();
}

// 64 persistent blocks (1/CU). Block = (d, hb): owns h cols [hb*16, hb*16+16).
__global__ __launch_bounds__(256, 1) void k_scan(
    const float* __restrict__ Whf, const u16* __restrict__ gx,
    u16* __restrict__ hbuf,     // [pp=2][d=2][128][512] bf16, parity = global t
    u16* __restrict__ xout,     // [32768][1024] bf16 (concat dirs)
    float* __restrict__ cbuf,   // [2][128][512] f32
    u32* cnt, u32 base, int t0)
{
  int tid = threadIdx.x, lane = tid & 63, w = tid >> 6;
  int d = blockIdx.x >> 5, hb = blockIdx.x & 31;
  __shared__ u16 WhL[64 * 512];
  for (int i = tid; i < 64 * 512; i += 256) {
    int r = i >> 9, k = i & 511;
    int grow = (r >> 4) * 512 + hb * 16 + (r & 15);       // gate row q*512 + hb*16 + u
    WhL[(r << 9) + (k ^ ((r & 7) << 3))] = f2bf(Whf[((size_t)d * 2048 + grow) * 512 + k]);
  }

  int bb = w * 32;                 // wave owns batch rows [bb, bb+32)
  int l15 = lane & 15, l4 = lane >> 4;
  u32 ord = base;
  float c[2][4];
  if (t0 == 0) {
    #pragma unroll
    for (int mt = 0; mt < 2; ++mt)
      #pragma unroll
      for (int r = 0; r < 4; ++r) c[mt][r] = 0.f;
    // zero own h_{-1} cols (pp=0) with coherent u64 stores
    for (int i = tid; i < 512; i += 256) {
      int b = i >> 2, j = i & 3;
      u64* p = (u64*)(hbuf + ((size_t)d * 128 + b) * 512 + hb * 16) + j;
      __hip_atomic_store(p, 0ull, __ATOMIC_RELAXED, __HIP_MEMORY_SCOPE_AGENT);
    }
    ++ord;
    gridbar(cnt, 64u * ord);
  } else {
    #pragma unroll
    for (int mt = 0; mt < 2; ++mt)
      #pragma unroll
      for (int r = 0; r < 4; ++r) {
        int b = bb + mt * 16 + l4 * 4 + r;
        c[mt][r] = cbuf[((size_t)d * 128 + b) * 512 + hb * 16 + l15];
      }
    __syncthreads();   // WhL staging complete
  }

  for (int tt = 0; tt < TCH; ++tt) {
    int t = t0 + tt;
    // gates_x loads (plain, L2/L3-warm) — issued first, latency hides under h burst
    const u16* gxt = gx + (((size_t)d * 32 + hb) * TCH + tt) * 8192;
    u16 gxv[2][4][4];
    #pragma unroll
    for (int mt = 0; mt < 2; ++mt)
      #pragma unroll
      for (int q = 0; q < 4; ++q)
        #pragma unroll
        for (int r = 0; r < 4; ++r) {
          int b = bb + mt * 16 + l4 * 4 + r;
          gxv[mt][q][r] = gxt[(q * 128 + b) * 16 + l15];
        }
    // h(t-1) coherent loads: issue all 32, single wait before use
    const u16* hp = hbuf + ((size_t)(t & 1) * 2 + d) * 128 * 512;
    const u16* hpA = hp + (size_t)(bb + l15) * 512 + l4 * 8;
    const u16* hpB = hp + (size_t)(bb + 16 + l15) * 512 + l4 * 8;
    bf16x8 a0s[16], a1s[16];
    #pragma unroll
    for (int kk = 0; kk < 16; ++kk) {
      a0s[kk] = ldh16(hpA + kk * 32);
      a1s[kk] = ldh16(hpB + kk * 32);
    }
    f32x4 acc[2][4];
    #pragma unroll
    for (int mt = 0; mt < 2; ++mt)
      #pragma unroll
      for (int q = 0; q < 4; ++q) acc[mt][q] = f32x4{0.f, 0.f, 0.f, 0.f};
    #pragma unroll
    for (int kk = 0; kk < 16; ++kk) {
      int kbase = kk * 32 + l4 * 8;
      #pragma unroll
      for (int q = 0; q < 4; ++q) {
        int r = q * 16 + l15;
        bf16x8 bv = *(const bf16x8*)(&WhL[(r << 9) + (kbase ^ ((r & 7) << 3))]);
        acc[0][q] = __builtin_amdgcn_mfma_f32_16x16x32_bf16(a0s[kk], bv, acc[0][q], 0, 0, 0);
        acc[1][q] = __builtin_amdgcn_mfma_f32_16x16x32_bf16(a1s[kk], bv, acc[1][q], 0, 0, 0);
      }
    }
    u16* ho = hbuf + ((size_t)((t + 1) & 1) * 2 + d) * 128 * 512;
    #pragma unroll
    for (int mt = 0; mt < 2; ++mt)
      #pragma unroll
      for (int r = 0; r < 4; ++r) {
        int b = bb + mt * 16 + l4 * 4 + r;
        float gi = acc[mt][0][r] + bf2f(gxv[mt][0][r]);
        float gf = acc[mt][1][r] + bf2f(gxv[mt][1][r]);
        float gg = acc[mt][2][r] + bf2f(gxv[mt][2][r]);
        float go = acc[mt][3][r] + bf2f(gxv[mt][3][r]);
        float cn = sigm(gf) * c[mt][r] + sigm(gi) * tanh_(gg);
        float hn = sigm(go) * tanh_(cn);
        c[mt][r] = cn;
        u16 hv = f2bf(hn);
        sth(ho + (size_t)b * 512 + hb * 16 + l15, hv);                      // coherent
        xout[((size_t)t * 128 + b) * 1024 + d * 512 + hb * 16 + l15] = hv;  // cached
      }
    if (tt < TCH - 1) { ++ord; gridbar(cnt, 64u * ord); }
  }
  #pragma unroll
  for (int mt = 0; mt < 2; ++mt)
    #pragma unroll
    for (int r = 0; r < 4; ++r) {
      int b = bb + mt * 16 + l4 * 4 + r;
      cbuf[((size_t)d * 128 + b) * 512 + hb * 16 + l15] = c[mt][r];
    }
}

// ---------------- final: max over directions ----------------
__global__ void k_final(const u16* __restrict__ xin, float* __restrict__ out, int n) {
  int i = blockIdx.x * 256 + threadIdx.x;
  if (i >= n) return;
  int nrow = i >> 9, j = i & 511;
  float a = bf2f(xin[(size_t)nrow * 1024 + j]);
  float b = bf2f(xin[(size_t)nrow * 1024 + 512 + j]);
  out[i] = fmaxf(a, b);
}

extern "C" void kernel_launch(void* const* d_in, const int* in_sizes, int n_in,
                              void* d_out, int out_size, void* d_ws, size_t ws_size,
                              hipStream_t stream) {
  (void)in_sizes; (void)n_in; (void)out_size; (void)ws_size;
  const int*   tokens = (const int*)d_in[0];
  const float* embedW = (const float*)d_in[1];
  const float* W_ih0  = (const float*)d_in[2];
  const float* W_hh0  = (const float*)d_in[3];
  const float* b_ih0  = (const float*)d_in[4];
  const float* b_hh0  = (const float*)d_in[5];
  const float* W_ih   = (const float*)d_in[6];
  const float* W_hh   = (const float*)d_in[7];
  const float* b_ih   = (const float*)d_in[8];
  const float* b_hh   = (const float*)d_in[9];

  char* ws = (char*)d_ws;
  size_t off = 0;
  auto alloc = [&](size_t bytes) { void* p = ws + off; off += (bytes + 255) & ~(size_t)255; return p; };
  u16*   Wi_bf = (u16*)alloc(18087936ull * 2);   // [2][2048][320] + [4][2][2048][1024]
  float* biasC = (float*)alloc(20480ull * 4);    // [5][2][2048]
  u16*   Xbuf  = (u16*)alloc(33554432ull * 2);   // [32768][1024] single activation buffer
  u16*   gxbuf = (u16*)alloc(16777216ull * 2);   // [2][32][TCH][4][128][16] one chunk
  u16*   hbuf  = (u16*)alloc(262144ull * 2);     // [2][2][128][512]
  float* cbuf  = (float*)alloc(131072ull * 4);   // [2][128][512]
  u32*   flags = (u32*)alloc(256);               // monotonic barrier counter
  // total ~132 MB

  hipMemsetAsync(flags, 0, 256, stream);

  k_cvt<<<1024, 256, 0, stream>>>(W_ih0, Wi_bf, 1310720);
  k_cvt<<<4096, 256, 0, stream>>>(W_ih,  Wi_bf + 1310720, 16777216);
  k_bias<<<80, 256, 0, stream>>>(b_ih0, b_hh0, b_ih, b_hh, biasC);

  u32 bar = 0;
  for (int l = 0; l < 5; ++l) {
    int K = l ? 1024 : 320;
    const u16*   Wi_l  = l ? (Wi_bf + 1310720 + (size_t)(l - 1) * 4194304) : Wi_bf;
    const float* Whf_l = l ? (W_hh + (size_t)(l - 1) * 2097152) : W_hh0;
    const float* bias_l = biasC + (size_t)l * 4096;
    const float* embA = (l == 0) ? embedW : nullptr;
    const int*   tokA = (l == 0) ? tokens : nullptr;
    for (int ch = 0; ch < 256 / TCH; ++ch) {
      int t0 = ch * TCH;
      dim3 gg(32, TCH, 1);
      k_gemm<<<gg, 256, 0, stream>>>(Xbuf, embA, tokA, Wi_l, bias_l, gxbuf, K, t0);
      k_scan<<<64, 256, 0, stream>>>(Whf_l, gxbuf, hbuf, Xbuf, cbuf, flags, bar, t0);
      bar += (t0 == 0) ? TCH : (TCH - 1);
    }
  }
  k_final<<<65536, 256, 0, stream>>>(Xbuf, (float*)d_out, 16777216);
}